// Round 3
// baseline (1536.470 us; speedup 1.0000x reference)
//
#include <hip/hip_runtime.h>

#define Bq 16
#define Sq 512
#define Dq 400
#define Vq 32000
#define Tq 8
#define NSq 30
#define NGq 3
#define BTq (Bq*Tq)                     // 128
#define D3q (3*Dq)                      // 1200
#define SLICE 4096000                   // Bq*Tq*Vq, one ptr slice (elems)
#define PTR_TOTAL (30ull*SLICE)         // 122,880,000
#define GATE_TOTAL (NSq*Bq*NGq)         // 1440

__device__ inline float sigmoidf_(float x) { return 1.0f / (1.0f + __expf(-x)); }

__device__ inline float blockReduceSum(float v, float* red) {
    int tid = threadIdx.x;
    #pragma unroll
    for (int o = 32; o > 0; o >>= 1) v += __shfl_down(v, o, 64);
    if ((tid & 63) == 0) red[tid >> 6] = v;
    __syncthreads();
    if (tid == 0) {
        float s = red[0];
        int nw = blockDim.x >> 6;
        for (int i = 1; i < nw; i++) s += red[i];
        red[0] = s;
    }
    __syncthreads();
    float r = red[0];
    __syncthreads();
    return r;
}

__device__ inline float blockReduceMax(float v, float* red) {
    int tid = threadIdx.x;
    #pragma unroll
    for (int o = 32; o > 0; o >>= 1) v = fmaxf(v, __shfl_down(v, o, 64));
    if ((tid & 63) == 0) red[tid >> 6] = v;
    __syncthreads();
    if (tid == 0) {
        float s = red[0];
        int nw = blockDim.x >> 6;
        for (int i = 1; i < nw; i++) s = fmaxf(s, red[i]);
        red[0] = s;
    }
    __syncthreads();
    float r = red[0];
    __syncthreads();
    return r;
}

// GRU-like prep: X, gi, gh, h  (one block per (b,t))
__global__ void k_prep(const float* __restrict__ enc_hidden, const float* __restrict__ shared_emb,
                       const float* __restrict__ slot_emb, const float* __restrict__ w_ih,
                       const float* __restrict__ w_hh, const float* __restrict__ b_ih,
                       const float* __restrict__ b_hh, const int* __restrict__ trg,
                       float* __restrict__ h_out, float* __restrict__ X_out) {
    __shared__ float x_l[Dq], h0_l[Dq], gi_l[D3q], gh_l[D3q];
    int bt = blockIdx.x, b = bt >> 3, t = bt & 7;
    int tid = threadIdx.x;
    int tok = (t == 0) ? 0 : trg[b * NSq * Tq + (t - 1)];
    for (int d = tid; d < Dq; d += blockDim.x) {
        x_l[d] = (t == 0) ? slot_emb[d] : shared_emb[(size_t)tok * Dq + d];
        h0_l[d] = enc_hidden[b * Dq + d];
    }
    __syncthreads();
    for (int j = tid; j < D3q; j += blockDim.x) {
        const float4* wi4 = (const float4*)(w_ih + (size_t)j * Dq);
        const float4* wh4 = (const float4*)(w_hh + (size_t)j * Dq);
        float ai = b_ih[j], ah = b_hh[j];
        for (int q = 0; q < Dq / 4; ++q) {
            float4 pi = wi4[q], ph = wh4[q];
            int k = 4 * q;
            ai += x_l[k]*pi.x + x_l[k+1]*pi.y + x_l[k+2]*pi.z + x_l[k+3]*pi.w;
            ah += h0_l[k]*ph.x + h0_l[k+1]*ph.y + h0_l[k+2]*ph.z + h0_l[k+3]*ph.w;
        }
        gi_l[j] = ai; gh_l[j] = ah;
    }
    __syncthreads();
    for (int d = tid; d < Dq; d += blockDim.x) {
        float r = sigmoidf_(gi_l[d] + gh_l[d]);
        float z = sigmoidf_(gi_l[Dq + d] + gh_l[Dq + d]);
        float n = tanhf(gi_l[2 * Dq + d] + r * gh_l[2 * Dq + d]);
        float h = (1.0f - z) * n + z * h0_l[d];
        h_out[bt * Dq + d] = h;
        X_out[bt * Dq + d] = x_l[d];
    }
}

// scores, softmax probs, context (RAW scores!), p_gen, gate0.  block=512, one per (b,t)
__global__ void k_attn(const float* __restrict__ hbuf, const float* __restrict__ Xbuf,
                       const float* __restrict__ enc_out, const float* __restrict__ w_ratio_w,
                       const float* __restrict__ w_ratio_b, const float* __restrict__ w_gate_w,
                       const float* __restrict__ w_gate_b,
                       float* __restrict__ probs, float* __restrict__ pgen,
                       float* __restrict__ out_gate) {
    __shared__ float h_l[Dq], ctx_l[Dq], sc_l[Sq], red[8];
    int bt = blockIdx.x, b = bt >> 3, t = bt & 7;
    int tid = threadIdx.x;
    for (int d = tid; d < Dq; d += 512) h_l[d] = hbuf[bt * Dq + d];
    __syncthreads();
    {   // scores: one s per thread
        const float4* e4 = (const float4*)(enc_out + ((size_t)(b * Sq + tid)) * Dq);
        float acc = 0.0f;
        for (int q = 0; q < Dq / 4; ++q) {
            float4 p = e4[q];
            int k = 4 * q;
            acc += h_l[k]*p.x + h_l[k+1]*p.y + h_l[k+2]*p.z + h_l[k+3]*p.w;
        }
        sc_l[tid] = acc;
    }
    __syncthreads();
    float myv = sc_l[tid];
    float m = blockReduceMax(myv, red);
    float e = __expf(myv - m);
    float ssum = blockReduceSum(e, red);
    probs[bt * Sq + tid] = e / ssum;
    // context from RAW scores
    for (int d = tid; d < Dq; d += 512) {
        float acc = 0.0f;
        for (int s = 0; s < Sq; ++s)
            acc += sc_l[s] * enc_out[((size_t)(b * Sq + s)) * Dq + d];
        ctx_l[d] = acc;
    }
    __syncthreads();
    {   // p_gen = sigmoid([h,ctx,X] . w_ratio + b)
        float part = 0.0f;
        for (int i = tid; i < D3q; i += 512) {
            float v = (i < Dq) ? h_l[i] : (i < 2 * Dq ? ctx_l[i - Dq] : Xbuf[bt * Dq + (i - 2 * Dq)]);
            part += v * w_ratio_w[i];
        }
        float tot = blockReduceSum(part, red);
        if (tid == 0) pgen[bt] = sigmoidf_(tot + w_ratio_b[0]);
    }
    if (t == 0) {
        for (int g = 0; g < NGq; ++g) {
            float part = 0.0f;
            for (int d = tid; d < Dq; d += 512) part += ctx_l[d] * w_gate_w[g * Dq + d];
            float tot = blockReduceSum(part, red);
            if (tid == 0) out_gate[b * NGq + g] = tot + w_gate_b[g];
        }
    }
}

// p_ctx scatter-add
__global__ void k_scatter(const int* __restrict__ story, const float* __restrict__ probs,
                          float* __restrict__ pctx) {
    int bt = blockIdx.x, b = bt >> 3, s = threadIdx.x;
    int tok = story[b * Sq + s];
    atomicAdd(&pctx[(size_t)bt * Vq + tok], probs[bt * Sq + s]);
}

// logits = h @ shared_emb^T : 128 x 32000, K=400.
// 16-row tile in LDS; 5 vocab columns per thread (amortize LDS b128 reads).
// grid (25, 8), block 256: block covers rows m0..m0+15, cols v0..v0+1279.
__global__ void k_logits(const float* __restrict__ hbuf, const float* __restrict__ emb,
                         float* __restrict__ logits) {
    __shared__ float ht[16][Dq];
    int m0 = blockIdx.y * 16;
    int tid = threadIdx.x;
    for (int i = tid; i < 16 * Dq; i += 256) ht[i / Dq][i % Dq] = hbuf[(m0 + i / Dq) * Dq + (i % Dq)];
    __syncthreads();
    int v0 = blockIdx.x * 1280 + tid;
    const float4* e0 = (const float4*)(emb + (size_t)(v0          ) * Dq);
    const float4* e1 = (const float4*)(emb + (size_t)(v0 +  256   ) * Dq);
    const float4* e2 = (const float4*)(emb + (size_t)(v0 +  512   ) * Dq);
    const float4* e3 = (const float4*)(emb + (size_t)(v0 +  768   ) * Dq);
    const float4* e4p = (const float4*)(emb + (size_t)(v0 + 1024  ) * Dq);
    float acc[5][16];
    #pragma unroll
    for (int j = 0; j < 5; ++j)
        #pragma unroll
        for (int m = 0; m < 16; ++m) acc[j][m] = 0.0f;
    for (int q = 0; q < Dq / 4; ++q) {
        float4 ev[5];
        ev[0] = e0[q]; ev[1] = e1[q]; ev[2] = e2[q]; ev[3] = e3[q]; ev[4] = e4p[q];
        #pragma unroll
        for (int m = 0; m < 16; ++m) {
            float4 hm = *(const float4*)&ht[m][4 * q];
            #pragma unroll
            for (int j = 0; j < 5; ++j)
                acc[j][m] += hm.x*ev[j].x + hm.y*ev[j].y + hm.z*ev[j].z + hm.w*ev[j].w;
        }
    }
    #pragma unroll
    for (int j = 0; j < 5; ++j)
        #pragma unroll
        for (int m = 0; m < 16; ++m)
            logits[(size_t)(m0 + m) * Vq + v0 + 256 * j] = acc[j][m];
}

// per-row max and 1/sum(exp)
__global__ void k_stats(const float* __restrict__ logits, float* __restrict__ rmax,
                        float* __restrict__ rinv) {
    __shared__ float red[8];
    int row = blockIdx.x, tid = threadIdx.x;
    const float* lr = logits + (size_t)row * Vq;
    float m = -1e30f;
    for (int v = tid; v < Vq; v += 256) m = fmaxf(m, lr[v]);
    m = blockReduceMax(m, red);
    float s = 0.0f;
    for (int v = tid; v < Vq; v += 256) s += __expf(lr[v] - m);
    s = blockReduceSum(s, red);
    if (tid == 0) { rmax[row] = m; rinv[row] = 1.0f / s; }
}

// p_final = p_gen*softmax(logits) + (1-p_gen)*p_ctx -> f32 slice 0
__global__ void k_combine(const float* __restrict__ logits, const float* __restrict__ pctx,
                          const float* __restrict__ rmax, const float* __restrict__ rinv,
                          const float* __restrict__ pgen, float* __restrict__ out) {
    int bt = blockIdx.y;
    int v = blockIdx.x * 256 + threadIdx.x;
    float m = rmax[bt], inv = rinv[bt], pg = pgen[bt];
    size_t idx = (size_t)bt * Vq + v;
    float pv = __expf(logits[idx] - m) * inv;
    out[idx] = pg * pv + (1.0f - pg) * pctx[idx];
}

extern "C" void kernel_launch(void* const* d_in, const int* in_sizes, int n_in,
                              void* d_out, int out_size, void* d_ws, size_t ws_size,
                              hipStream_t stream) {
    const float* enc_hidden = (const float*)d_in[0];
    const float* enc_out    = (const float*)d_in[1];
    const int*   story      = (const int*)d_in[2];
    const int*   trg        = (const int*)d_in[3];
    const float* shared_emb = (const float*)d_in[4];
    const float* slot_emb   = (const float*)d_in[5];
    const float* w_ih       = (const float*)d_in[6];
    const float* w_hh       = (const float*)d_in[7];
    const float* b_ih       = (const float*)d_in[8];
    const float* b_hh       = (const float*)d_in[9];
    const float* w_ratio_w  = (const float*)d_in[10];
    const float* w_ratio_b  = (const float*)d_in[11];
    const float* w_gate_w   = (const float*)d_in[12];
    const float* w_gate_b   = (const float*)d_in[13];

    float* out = (float*)d_out;

    // Scratch inside d_out's must-be-zero region (ptr slices 1..3), consumed
    // before the trailing memsets zero it. d_ws untouched.
    float* logits_buf = out + (size_t)SLICE;       // slice 1
    float* pctx_buf   = out + 2 * (size_t)SLICE;   // slice 2
    float* h_buf      = out + 3 * (size_t)SLICE;   // slice 3: 51,200 f
    float* X_buf      = h_buf + 51200;
    float* probs_buf  = X_buf + 51200;             // 65,536 f
    float* pgen_buf   = probs_buf + 65536;
    float* rmax_buf   = pgen_buf + 128;
    float* rinv_buf   = rmax_buf + 128;

    // zero-init only pctx (scatter-add target)
    hipMemsetAsync(pctx_buf, 0, (size_t)SLICE * sizeof(float), stream);

    hipLaunchKernelGGL(k_prep, dim3(BTq), dim3(256), 0, stream,
                       enc_hidden, shared_emb, slot_emb, w_ih, w_hh, b_ih, b_hh, trg, h_buf, X_buf);
    hipLaunchKernelGGL(k_attn, dim3(BTq), dim3(512), 0, stream,
                       h_buf, X_buf, enc_out, w_ratio_w, w_ratio_b, w_gate_w, w_gate_b,
                       probs_buf, pgen_buf, out + PTR_TOTAL);
    hipLaunchKernelGGL(k_scatter, dim3(BTq), dim3(Sq), 0, stream, story, probs_buf, pctx_buf);
    hipLaunchKernelGGL(k_logits, dim3(25, 8), dim3(256), 0, stream,
                       h_buf, shared_emb, logits_buf);
    hipLaunchKernelGGL(k_stats, dim3(BTq), dim3(256), 0, stream, logits_buf, rmax_buf, rinv_buf);
    hipLaunchKernelGGL(k_combine, dim3(Vq / 256, BTq), dim3(256), 0, stream,
                       logits_buf, pctx_buf, rmax_buf, rinv_buf, pgen_buf, out);

    // Zero everything that must be zero: ptr slices 1..29 (covers all scratch)
    // and gate slices 1..29. Stream-ordered after k_combine.
    hipMemsetAsync(out + (size_t)SLICE, 0, (PTR_TOTAL - SLICE) * sizeof(float), stream);
    hipMemsetAsync(out + PTR_TOTAL + Bq * NGq, 0,
                   (size_t)(GATE_TOTAL - Bq * NGq) * sizeof(float), stream);
}

// Round 6
// 850.777 us; speedup vs baseline: 1.8060x; 1.8060x over previous
//
#include <hip/hip_runtime.h>

#define Bq 16
#define Sq 512
#define Dq 400
#define Vq 32000
#define Tq 8
#define NSq 30
#define NGq 3
#define BTq (Bq*Tq)                     // 128
#define D3q (3*Dq)                      // 1200
#define SLICE 4096000                   // Bq*Tq*Vq, one ptr slice (elems)
#define PTR_TOTAL (30ull*SLICE)         // 122,880,000
#define GATE_TOTAL (NSq*Bq*NGq)         // 1440

__device__ inline float sigmoidf_(float x) { return 1.0f / (1.0f + __expf(-x)); }

__device__ inline float blockReduceSum(float v, float* red) {
    int tid = threadIdx.x;
    #pragma unroll
    for (int o = 32; o > 0; o >>= 1) v += __shfl_down(v, o, 64);
    if ((tid & 63) == 0) red[tid >> 6] = v;
    __syncthreads();
    if (tid == 0) {
        float s = red[0];
        int nw = blockDim.x >> 6;
        for (int i = 1; i < nw; i++) s += red[i];
        red[0] = s;
    }
    __syncthreads();
    float r = red[0];
    __syncthreads();
    return r;
}

__device__ inline float blockReduceMax(float v, float* red) {
    int tid = threadIdx.x;
    #pragma unroll
    for (int o = 32; o > 0; o >>= 1) v = fmaxf(v, __shfl_down(v, o, 64));
    if ((tid & 63) == 0) red[tid >> 6] = v;
    __syncthreads();
    if (tid == 0) {
        float s = red[0];
        int nw = blockDim.x >> 6;
        for (int i = 1; i < nw; i++) s = fmaxf(s, red[i]);
        red[0] = s;
    }
    __syncthreads();
    float r = red[0];
    __syncthreads();
    return r;
}

// GRU-like prep: X, gi, gh, h (+ hT for the logits GEMM). one block per (b,t)
__global__ void k_prep(const float* __restrict__ enc_hidden, const float* __restrict__ shared_emb,
                       const float* __restrict__ slot_emb, const float* __restrict__ w_ih,
                       const float* __restrict__ w_hh, const float* __restrict__ b_ih,
                       const float* __restrict__ b_hh, const int* __restrict__ trg,
                       float* __restrict__ h_out, float* __restrict__ hT_out,
                       float* __restrict__ X_out) {
    __shared__ float x_l[Dq], h0_l[Dq], gi_l[D3q], gh_l[D3q];
    int bt = blockIdx.x, b = bt >> 3, t = bt & 7;
    int tid = threadIdx.x;
    int tok = (t == 0) ? 0 : trg[b * NSq * Tq + (t - 1)];
    for (int d = tid; d < Dq; d += blockDim.x) {
        x_l[d] = (t == 0) ? slot_emb[d] : shared_emb[(size_t)tok * Dq + d];
        h0_l[d] = enc_hidden[b * Dq + d];
    }
    __syncthreads();
    for (int j = tid; j < D3q; j += blockDim.x) {
        const float4* wi4 = (const float4*)(w_ih + (size_t)j * Dq);
        const float4* wh4 = (const float4*)(w_hh + (size_t)j * Dq);
        float ai = b_ih[j], ah = b_hh[j];
        for (int q = 0; q < Dq / 4; ++q) {
            float4 pi = wi4[q], ph = wh4[q];
            int k = 4 * q;
            ai += x_l[k]*pi.x + x_l[k+1]*pi.y + x_l[k+2]*pi.z + x_l[k+3]*pi.w;
            ah += h0_l[k]*ph.x + h0_l[k+1]*ph.y + h0_l[k+2]*ph.z + h0_l[k+3]*ph.w;
        }
        gi_l[j] = ai; gh_l[j] = ah;
    }
    __syncthreads();
    for (int d = tid; d < Dq; d += blockDim.x) {
        float r = sigmoidf_(gi_l[d] + gh_l[d]);
        float z = sigmoidf_(gi_l[Dq + d] + gh_l[Dq + d]);
        float n = tanhf(gi_l[2 * Dq + d] + r * gh_l[2 * Dq + d]);
        float h = (1.0f - z) * n + z * h0_l[d];
        h_out[bt * Dq + d] = h;
        hT_out[d * BTq + bt] = h;
        X_out[bt * Dq + d] = x_l[d];
    }
}

// scores, softmax probs, context (RAW scores!), p_gen, gate0.  block=512, one per (b,t)
__global__ void k_attn(const float* __restrict__ hbuf, const float* __restrict__ Xbuf,
                       const float* __restrict__ enc_out, const float* __restrict__ w_ratio_w,
                       const float* __restrict__ w_ratio_b, const float* __restrict__ w_gate_w,
                       const float* __restrict__ w_gate_b,
                       float* __restrict__ probs, float* __restrict__ pgen,
                       float* __restrict__ out_gate) {
    __shared__ float h_l[Dq], ctx_l[Dq], sc_l[Sq], red[8];
    int bt = blockIdx.x, b = bt >> 3, t = bt & 7;
    int tid = threadIdx.x;
    for (int d = tid; d < Dq; d += 512) h_l[d] = hbuf[bt * Dq + d];
    __syncthreads();
    {   // scores: one s per thread
        const float4* e4 = (const float4*)(enc_out + ((size_t)(b * Sq + tid)) * Dq);
        float acc = 0.0f;
        for (int q = 0; q < Dq / 4; ++q) {
            float4 p = e4[q];
            int k = 4 * q;
            acc += h_l[k]*p.x + h_l[k+1]*p.y + h_l[k+2]*p.z + h_l[k+3]*p.w;
        }
        sc_l[tid] = acc;
    }
    __syncthreads();
    float myv = sc_l[tid];
    float m = blockReduceMax(myv, red);
    float e = __expf(myv - m);
    float ssum = blockReduceSum(e, red);
    probs[bt * Sq + tid] = e / ssum;
    // context from RAW scores
    for (int d = tid; d < Dq; d += 512) {
        float acc = 0.0f;
        for (int s = 0; s < Sq; ++s)
            acc += sc_l[s] * enc_out[((size_t)(b * Sq + s)) * Dq + d];
        ctx_l[d] = acc;
    }
    __syncthreads();
    {   // p_gen = sigmoid([h,ctx,X] . w_ratio + b)
        float part = 0.0f;
        for (int i = tid; i < D3q; i += 512) {
            float v = (i < Dq) ? h_l[i] : (i < 2 * Dq ? ctx_l[i - Dq] : Xbuf[bt * Dq + (i - 2 * Dq)]);
            part += v * w_ratio_w[i];
        }
        float tot = blockReduceSum(part, red);
        if (tid == 0) pgen[bt] = sigmoidf_(tot + w_ratio_b[0]);
    }
    if (t == 0) {
        for (int g = 0; g < NGq; ++g) {
            float part = 0.0f;
            for (int d = tid; d < Dq; d += 512) part += ctx_l[d] * w_gate_w[g * Dq + d];
            float tot = blockReduceSum(part, red);
            if (tid == 0) out_gate[b * NGq + g] = tot + w_gate_b[g];
        }
    }
}

// p_ctx scatter-add
__global__ void k_scatter(const int* __restrict__ story, const float* __restrict__ probs,
                          float* __restrict__ pctx) {
    int bt = blockIdx.x, b = bt >> 3, s = threadIdx.x;
    int tok = story[b * Sq + s];
    atomicAdd(&pctx[(size_t)bt * Vq + tok], probs[bt * Sq + s]);
}

// logits = h @ emb^T : [128 x 32000], K=400. LDS-staged tiled GEMM.
// grid = 250 (v-tiles of 128). block = 256. Per-thread 8bt x 8v register tile.
// K chunks of 40; embT/hT staged in LDS with +4 pad (row = 132 floats, 16B-aligned).
#define TVL 128
#define CKL 40
__global__ __launch_bounds__(256) void k_logits(const float* __restrict__ hT,
                                                const float* __restrict__ emb,
                                                float* __restrict__ logits) {
    __shared__ float eT[CKL][132];
    __shared__ float hL[CKL][132];
    int tid = threadIdx.x;
    int v0 = blockIdx.x * TVL;
    int tx = tid & 15, ty = tid >> 4;       // tx: v-group, ty: bt-group
    float acc[8][8];
    #pragma unroll
    for (int j = 0; j < 8; ++j)
        #pragma unroll
        for (int i = 0; i < 8; ++i) acc[j][i] = 0.0f;

    for (int c = 0; c < Dq / CKL; ++c) {
        int k0 = c * CKL;
        // stage hT chunk: 40x128 floats = 1280 float4-reads/4 -> 5 float4 per thread,
        // global reads fully coalesced (hT row-contiguous).
        const float4* hg = (const float4*)(hT + (size_t)k0 * BTq);
        #pragma unroll
        for (int r = 0; r < 5; ++r) {
            int idx = tid + 256 * r;            // 0..1279
            int k = idx >> 5, c4 = idx & 31;    // row k, float4 col c4
            float4 vd = hg[idx];
            *(float4*)&hL[k][4 * c4] = vd;
        }
        // stage emb chunk transposed: 128 rows x 10 float4 along k (row-contiguous reads)
        #pragma unroll
        for (int r = 0; r < 5; ++r) {
            int idx = tid + 256 * r;            // 0..1279
            int v = idx / 10, q = idx - 10 * v; // v row, q: float4 within 40-chunk
            float4 vd = *(const float4*)(emb + (size_t)(v0 + v) * Dq + k0 + 4 * q);
            eT[4*q+0][v] = vd.x; eT[4*q+1][v] = vd.y; eT[4*q+2][v] = vd.z; eT[4*q+3][v] = vd.w;
        }
        __syncthreads();
        #pragma unroll 4
        for (int k = 0; k < CKL; ++k) {
            float4 h0 = *(const float4*)&hL[k][8 * ty];
            float4 h1 = *(const float4*)&hL[k][8 * ty + 4];
            float4 e0 = *(const float4*)&eT[k][8 * tx];
            float4 e1 = *(const float4*)&eT[k][8 * tx + 4];
            float hv[8] = {h0.x, h0.y, h0.z, h0.w, h1.x, h1.y, h1.z, h1.w};
            float ev[8] = {e0.x, e0.y, e0.z, e0.w, e1.x, e1.y, e1.z, e1.w};
            #pragma unroll
            for (int j = 0; j < 8; ++j)
                #pragma unroll
                for (int i = 0; i < 8; ++i)
                    acc[j][i] += hv[j] * ev[i];
        }
        __syncthreads();
    }
    #pragma unroll
    for (int j = 0; j < 8; ++j) {
        int bt = 8 * ty + j;
        float* dst = logits + (size_t)bt * Vq + v0 + 8 * tx;
        *(float4*)dst       = make_float4(acc[j][0], acc[j][1], acc[j][2], acc[j][3]);
        *(float4*)(dst + 4) = make_float4(acc[j][4], acc[j][5], acc[j][6], acc[j][7]);
    }
}

// per-row max and 1/sum(exp)
__global__ void k_stats(const float* __restrict__ logits, float* __restrict__ rmax,
                        float* __restrict__ rinv) {
    __shared__ float red[8];
    int row = blockIdx.x, tid = threadIdx.x;
    const float* lr = logits + (size_t)row * Vq;
    float m = -1e30f;
    for (int v = tid; v < Vq; v += 256) m = fmaxf(m, lr[v]);
    m = blockReduceMax(m, red);
    float s = 0.0f;
    for (int v = tid; v < Vq; v += 256) s += __expf(lr[v] - m);
    s = blockReduceSum(s, red);
    if (tid == 0) { rmax[row] = m; rinv[row] = 1.0f / s; }
}

// p_final = p_gen*softmax(logits) + (1-p_gen)*p_ctx -> f32 slice 0
__global__ void k_combine(const float* __restrict__ logits, const float* __restrict__ pctx,
                          const float* __restrict__ rmax, const float* __restrict__ rinv,
                          const float* __restrict__ pgen, float* __restrict__ out) {
    int bt = blockIdx.y;
    int v = blockIdx.x * 256 + threadIdx.x;
    float m = rmax[bt], inv = rinv[bt], pg = pgen[bt];
    size_t idx = (size_t)bt * Vq + v;
    float pv = __expf(logits[idx] - m) * inv;
    out[idx] = pg * pv + (1.0f - pg) * pctx[idx];
}

extern "C" void kernel_launch(void* const* d_in, const int* in_sizes, int n_in,
                              void* d_out, int out_size, void* d_ws, size_t ws_size,
                              hipStream_t stream) {
    const float* enc_hidden = (const float*)d_in[0];
    const float* enc_out    = (const float*)d_in[1];
    const int*   story      = (const int*)d_in[2];
    const int*   trg        = (const int*)d_in[3];
    const float* shared_emb = (const float*)d_in[4];
    const float* slot_emb   = (const float*)d_in[5];
    const float* w_ih       = (const float*)d_in[6];
    const float* w_hh       = (const float*)d_in[7];
    const float* b_ih       = (const float*)d_in[8];
    const float* b_hh       = (const float*)d_in[9];
    const float* w_ratio_w  = (const float*)d_in[10];
    const float* w_ratio_b  = (const float*)d_in[11];
    const float* w_gate_w   = (const float*)d_in[12];
    const float* w_gate_b   = (const float*)d_in[13];

    float* out = (float*)d_out;

    // Scratch inside d_out's must-be-zero region (ptr slices 1..3), consumed
    // before the trailing memsets zero it.
    float* logits_buf = out + (size_t)SLICE;       // slice 1
    float* pctx_buf   = out + 2 * (size_t)SLICE;   // slice 2
    float* h_buf      = out + 3 * (size_t)SLICE;   // slice 3: 51,200 f
    float* X_buf      = h_buf + 51200;
    float* probs_buf  = X_buf + 51200;             // 65,536 f
    float* pgen_buf   = probs_buf + 65536;
    float* rmax_buf   = pgen_buf + 128;
    float* rinv_buf   = rmax_buf + 128;
    float* hT_buf     = rinv_buf + 128;            // 51,200 f (h transposed [d][bt])

    // zero-init only pctx (scatter-add target)
    hipMemsetAsync(pctx_buf, 0, (size_t)SLICE * sizeof(float), stream);

    hipLaunchKernelGGL(k_prep, dim3(BTq), dim3(256), 0, stream,
                       enc_hidden, shared_emb, slot_emb, w_ih, w_hh, b_ih, b_hh, trg,
                       h_buf, hT_buf, X_buf);
    hipLaunchKernelGGL(k_attn, dim3(BTq), dim3(512), 0, stream,
                       h_buf, X_buf, enc_out, w_ratio_w, w_ratio_b, w_gate_w, w_gate_b,
                       probs_buf, pgen_buf, out + PTR_TOTAL);
    hipLaunchKernelGGL(k_scatter, dim3(BTq), dim3(Sq), 0, stream, story, probs_buf, pctx_buf);
    hipLaunchKernelGGL(k_logits, dim3(Vq / TVL), dim3(256), 0, stream,
                       hT_buf, shared_emb, logits_buf);
    hipLaunchKernelGGL(k_stats, dim3(BTq), dim3(256), 0, stream, logits_buf, rmax_buf, rinv_buf);
    hipLaunchKernelGGL(k_combine, dim3(Vq / 256, BTq), dim3(256), 0, stream,
                       logits_buf, pctx_buf, rmax_buf, rinv_buf, pgen_buf, out);

    // Zero everything that must be zero: ptr slices 1..29 (covers all scratch)
    // and gate slices 1..29. Stream-ordered after k_combine.
    hipMemsetAsync(out + (size_t)SLICE, 0, (PTR_TOTAL - SLICE) * sizeof(float), stream);
    hipMemsetAsync(out + PTR_TOTAL + Bq * NGq, 0,
                   (size_t)(GATE_TOTAL - Bq * NGq) * sizeof(float), stream);
}

// Round 9
// 804.076 us; speedup vs baseline: 1.9109x; 1.0581x over previous
//
#include <hip/hip_runtime.h>

#define Bq 16
#define Sq 512
#define Dq 400
#define Vq 32000
#define Tq 8
#define NSq 30
#define NGq 3
#define BTq (Bq*Tq)                     // 128
#define D3q (3*Dq)                      // 1200
#define SLICE 4096000                   // Bq*Tq*Vq, one ptr slice (elems)
#define PTR_TOTAL (30ull*SLICE)         // 122,880,000
#define GATE_TOTAL (NSq*Bq*NGq)         // 1440

// k_logits fused grid: 250 compute blocks + zero-fill blocks
#define NCOMPUTE 250
#define NZERO 1813                      // 29*SLICE/4 = 29,696,000 float4; 16384/block
#define ZPER 16384                      // float4 per zero block (64 per thread)

__device__ inline float sigmoidf_(float x) { return 1.0f / (1.0f + __expf(-x)); }

__device__ inline float blockReduceSum(float v, float* red) {
    int tid = threadIdx.x;
    #pragma unroll
    for (int o = 32; o > 0; o >>= 1) v += __shfl_down(v, o, 64);
    if ((tid & 63) == 0) red[tid >> 6] = v;
    __syncthreads();
    if (tid == 0) {
        float s = red[0];
        int nw = blockDim.x >> 6;
        for (int i = 1; i < nw; i++) s += red[i];
        red[0] = s;
    }
    __syncthreads();
    float r = red[0];
    __syncthreads();
    return r;
}

__device__ inline float blockReduceMax(float v, float* red) {
    int tid = threadIdx.x;
    #pragma unroll
    for (int o = 32; o > 0; o >>= 1) v = fmaxf(v, __shfl_down(v, o, 64));
    if ((tid & 63) == 0) red[tid >> 6] = v;
    __syncthreads();
    if (tid == 0) {
        float s = red[0];
        int nw = blockDim.x >> 6;
        for (int i = 1; i < nw; i++) s = fmaxf(s, red[i]);
        red[0] = s;
    }
    __syncthreads();
    float r = red[0];
    __syncthreads();
    return r;
}

// GRU-like prep: X, gi, gh, h (+ hT for the logits GEMM). one block per (b,t)
__global__ void k_prep(const float* __restrict__ enc_hidden, const float* __restrict__ shared_emb,
                       const float* __restrict__ slot_emb, const float* __restrict__ w_ih,
                       const float* __restrict__ w_hh, const float* __restrict__ b_ih,
                       const float* __restrict__ b_hh, const int* __restrict__ trg,
                       float* __restrict__ h_out, float* __restrict__ hT_out,
                       float* __restrict__ X_out) {
    __shared__ float x_l[Dq], h0_l[Dq], gi_l[D3q], gh_l[D3q];
    int bt = blockIdx.x, b = bt >> 3, t = bt & 7;
    int tid = threadIdx.x;
    int tok = (t == 0) ? 0 : trg[b * NSq * Tq + (t - 1)];
    for (int d = tid; d < Dq; d += blockDim.x) {
        x_l[d] = (t == 0) ? slot_emb[d] : shared_emb[(size_t)tok * Dq + d];
        h0_l[d] = enc_hidden[b * Dq + d];
    }
    __syncthreads();
    for (int j = tid; j < D3q; j += blockDim.x) {
        const float4* wi4 = (const float4*)(w_ih + (size_t)j * Dq);
        const float4* wh4 = (const float4*)(w_hh + (size_t)j * Dq);
        float ai = b_ih[j], ah = b_hh[j];
        for (int q = 0; q < Dq / 4; ++q) {
            float4 pi = wi4[q], ph = wh4[q];
            int k = 4 * q;
            ai += x_l[k]*pi.x + x_l[k+1]*pi.y + x_l[k+2]*pi.z + x_l[k+3]*pi.w;
            ah += h0_l[k]*ph.x + h0_l[k+1]*ph.y + h0_l[k+2]*ph.z + h0_l[k+3]*ph.w;
        }
        gi_l[j] = ai; gh_l[j] = ah;
    }
    __syncthreads();
    for (int d = tid; d < Dq; d += blockDim.x) {
        float r = sigmoidf_(gi_l[d] + gh_l[d]);
        float z = sigmoidf_(gi_l[Dq + d] + gh_l[Dq + d]);
        float n = tanhf(gi_l[2 * Dq + d] + r * gh_l[2 * Dq + d]);
        float h = (1.0f - z) * n + z * h0_l[d];
        h_out[bt * Dq + d] = h;
        hT_out[d * BTq + bt] = h;
        X_out[bt * Dq + d] = x_l[d];
    }
}

// scores, softmax probs, context (RAW scores!), p_gen, gate0.  block=512, one per (b,t)
__global__ void k_attn(const float* __restrict__ hbuf, const float* __restrict__ Xbuf,
                       const float* __restrict__ enc_out, const float* __restrict__ w_ratio_w,
                       const float* __restrict__ w_ratio_b, const float* __restrict__ w_gate_w,
                       const float* __restrict__ w_gate_b,
                       float* __restrict__ probs, float* __restrict__ pgen,
                       float* __restrict__ out_gate) {
    __shared__ float h_l[Dq], ctx_l[Dq], sc_l[Sq], red[8];
    int bt = blockIdx.x, b = bt >> 3, t = bt & 7;
    int tid = threadIdx.x;
    for (int d = tid; d < Dq; d += 512) h_l[d] = hbuf[bt * Dq + d];
    __syncthreads();
    {   // scores: one s per thread
        const float4* e4 = (const float4*)(enc_out + ((size_t)(b * Sq + tid)) * Dq);
        float acc = 0.0f;
        for (int q = 0; q < Dq / 4; ++q) {
            float4 p = e4[q];
            int k = 4 * q;
            acc += h_l[k]*p.x + h_l[k+1]*p.y + h_l[k+2]*p.z + h_l[k+3]*p.w;
        }
        sc_l[tid] = acc;
    }
    __syncthreads();
    float myv = sc_l[tid];
    float m = blockReduceMax(myv, red);
    float e = __expf(myv - m);
    float ssum = blockReduceSum(e, red);
    probs[bt * Sq + tid] = e / ssum;
    // context from RAW scores; unroll 8 -> 8 outstanding loads to hide L2 latency
    for (int d = tid; d < Dq; d += 512) {
        float acc = 0.0f;
        #pragma unroll 8
        for (int s = 0; s < Sq; ++s)
            acc += sc_l[s] * enc_out[((size_t)(b * Sq + s)) * Dq + d];
        ctx_l[d] = acc;
    }
    __syncthreads();
    {   // p_gen = sigmoid([h,ctx,X] . w_ratio + b)
        float part = 0.0f;
        for (int i = tid; i < D3q; i += 512) {
            float v = (i < Dq) ? h_l[i] : (i < 2 * Dq ? ctx_l[i - Dq] : Xbuf[bt * Dq + (i - 2 * Dq)]);
            part += v * w_ratio_w[i];
        }
        float tot = blockReduceSum(part, red);
        if (tid == 0) pgen[bt] = sigmoidf_(tot + w_ratio_b[0]);
    }
    if (t == 0) {
        for (int g = 0; g < NGq; ++g) {
            float part = 0.0f;
            for (int d = tid; d < Dq; d += 512) part += ctx_l[d] * w_gate_w[g * Dq + d];
            float tot = blockReduceSum(part, red);
            if (tid == 0) out_gate[b * NGq + g] = tot + w_gate_b[g];
        }
    }
}

// p_ctx scatter-add
__global__ void k_scatter(const int* __restrict__ story, const float* __restrict__ probs,
                          float* __restrict__ pctx) {
    int bt = blockIdx.x, b = bt >> 3, s = threadIdx.x;
    int tok = story[b * Sq + s];
    atomicAdd(&pctx[(size_t)bt * Vq + tok], probs[bt * Sq + s]);
}

// Fused: [0,250) logits GEMM blocks; [250,250+1813) zero ptr slices 1..29;
// last block zeroes gate slices 1..29. Zero-write BW overlaps GEMM compute.
#define TVL 128
#define CKL 40
__global__ __launch_bounds__(256) void k_logits(const float* __restrict__ hT,
                                                const float* __restrict__ emb,
                                                float* __restrict__ logits,
                                                float* __restrict__ out) {
    __shared__ float eT[CKL][132];
    __shared__ float hL[CKL][132];
    int bid = blockIdx.x;
    int tid = threadIdx.x;
    if (bid >= NCOMPUTE) {
        int zb = bid - NCOMPUTE;
        float4 z = make_float4(0.0f, 0.0f, 0.0f, 0.0f);
        if (zb < NZERO) {
            float4* dst = (float4*)(out + (size_t)SLICE);
            const size_t total = 29ull * SLICE / 4;   // 29,696,000 float4
            size_t base = (size_t)zb * ZPER + tid;
            #pragma unroll
            for (int r = 0; r < ZPER / 256; ++r) {
                size_t idx = base + (size_t)r * 256;
                if (idx < total) dst[idx] = z;
            }
        } else {
            // gate slices 1..29: 1392 floats = 348 float4
            float4* g = (float4*)(out + PTR_TOTAL + Bq * NGq);
            for (int i = tid; i < (GATE_TOTAL - Bq * NGq) / 4; i += 256) g[i] = z;
        }
        return;
    }
    int v0 = bid * TVL;
    int tx = tid & 15, ty = tid >> 4;       // tx: v-group, ty: bt-group
    float acc[8][8];
    #pragma unroll
    for (int j = 0; j < 8; ++j)
        #pragma unroll
        for (int i = 0; i < 8; ++i) acc[j][i] = 0.0f;

    for (int c = 0; c < Dq / CKL; ++c) {
        int k0 = c * CKL;
        const float4* hg = (const float4*)(hT + (size_t)k0 * BTq);
        #pragma unroll
        for (int r = 0; r < 5; ++r) {
            int idx = tid + 256 * r;            // 0..1279
            int k = idx >> 5, c4 = idx & 31;    // row k, float4 col c4
            float4 vd = hg[idx];
            *(float4*)&hL[k][4 * c4] = vd;
        }
        #pragma unroll
        for (int r = 0; r < 5; ++r) {
            int idx = tid + 256 * r;            // 0..1279
            int v = idx / 10, q = idx - 10 * v; // v row, q: float4 within 40-chunk
            float4 vd = *(const float4*)(emb + (size_t)(v0 + v) * Dq + k0 + 4 * q);
            eT[4*q+0][v] = vd.x; eT[4*q+1][v] = vd.y; eT[4*q+2][v] = vd.z; eT[4*q+3][v] = vd.w;
        }
        __syncthreads();
        #pragma unroll 4
        for (int k = 0; k < CKL; ++k) {
            float4 h0 = *(const float4*)&hL[k][8 * ty];
            float4 h1 = *(const float4*)&hL[k][8 * ty + 4];
            float4 e0 = *(const float4*)&eT[k][8 * tx];
            float4 e1 = *(const float4*)&eT[k][8 * tx + 4];
            float hv[8] = {h0.x, h0.y, h0.z, h0.w, h1.x, h1.y, h1.z, h1.w};
            float ev[8] = {e0.x, e0.y, e0.z, e0.w, e1.x, e1.y, e1.z, e1.w};
            #pragma unroll
            for (int j = 0; j < 8; ++j)
                #pragma unroll
                for (int i = 0; i < 8; ++i)
                    acc[j][i] += hv[j] * ev[i];
        }
        __syncthreads();
    }
    #pragma unroll
    for (int j = 0; j < 8; ++j) {
        int bt = 8 * ty + j;
        float* dst = logits + (size_t)bt * Vq + v0 + 8 * tx;
        *(float4*)dst       = make_float4(acc[j][0], acc[j][1], acc[j][2], acc[j][3]);
        *(float4*)(dst + 4) = make_float4(acc[j][4], acc[j][5], acc[j][6], acc[j][7]);
    }
}

// per-row max and 1/sum(exp)
__global__ void k_stats(const float* __restrict__ logits, float* __restrict__ rmax,
                        float* __restrict__ rinv) {
    __shared__ float red[8];
    int row = blockIdx.x, tid = threadIdx.x;
    const float* lr = logits + (size_t)row * Vq;
    float m = -1e30f;
    for (int v = tid; v < Vq; v += 256) m = fmaxf(m, lr[v]);
    m = blockReduceMax(m, red);
    float s = 0.0f;
    for (int v = tid; v < Vq; v += 256) s += __expf(lr[v] - m);
    s = blockReduceSum(s, red);
    if (tid == 0) { rmax[row] = m; rinv[row] = 1.0f / s; }
}

// p_final = p_gen*softmax(logits) + (1-p_gen)*p_ctx -> f32 slice 0
__global__ void k_combine(const float* __restrict__ logits, const float* __restrict__ pctx,
                          const float* __restrict__ rmax, const float* __restrict__ rinv,
                          const float* __restrict__ pgen, float* __restrict__ out) {
    int bt = blockIdx.y;
    int v = blockIdx.x * 256 + threadIdx.x;
    float m = rmax[bt], inv = rinv[bt], pg = pgen[bt];
    size_t idx = (size_t)bt * Vq + v;
    float pv = __expf(logits[idx] - m) * inv;
    out[idx] = pg * pv + (1.0f - pg) * pctx[idx];
}

extern "C" void kernel_launch(void* const* d_in, const int* in_sizes, int n_in,
                              void* d_out, int out_size, void* d_ws, size_t ws_size,
                              hipStream_t stream) {
    const float* enc_hidden = (const float*)d_in[0];
    const float* enc_out    = (const float*)d_in[1];
    const int*   story      = (const int*)d_in[2];
    const int*   trg        = (const int*)d_in[3];
    const float* shared_emb = (const float*)d_in[4];
    const float* slot_emb   = (const float*)d_in[5];
    const float* w_ih       = (const float*)d_in[6];
    const float* w_hh       = (const float*)d_in[7];
    const float* b_ih       = (const float*)d_in[8];
    const float* b_hh       = (const float*)d_in[9];
    const float* w_ratio_w  = (const float*)d_in[10];
    const float* w_ratio_b  = (const float*)d_in[11];
    const float* w_gate_w   = (const float*)d_in[12];
    const float* w_gate_b   = (const float*)d_in[13];

    float* out = (float*)d_out;

    // All scratch in d_ws (ws_size ~1.97 GB per R6 fill evidence; need 33.6 MB).
    float* ws = (float*)d_ws;
    float* logits_buf = ws;                        // 4,096,000 f
    float* pctx_buf   = ws + (size_t)SLICE;        // 4,096,000 f
    float* h_buf      = ws + 2 * (size_t)SLICE;    // 51,200 f
    float* X_buf      = h_buf + 51200;
    float* probs_buf  = X_buf + 51200;             // 65,536 f
    float* pgen_buf   = probs_buf + 65536;
    float* rmax_buf   = pgen_buf + 128;
    float* rinv_buf   = rmax_buf + 128;
    float* hT_buf     = rinv_buf + 128;            // 51,200 f (h transposed [d][bt])

    // zero-init only pctx (scatter-add target)
    hipMemsetAsync(pctx_buf, 0, (size_t)SLICE * sizeof(float), stream);

    hipLaunchKernelGGL(k_prep, dim3(BTq), dim3(256), 0, stream,
                       enc_hidden, shared_emb, slot_emb, w_ih, w_hh, b_ih, b_hh, trg,
                       h_buf, hT_buf, X_buf);
    hipLaunchKernelGGL(k_attn, dim3(BTq), dim3(512), 0, stream,
                       h_buf, X_buf, enc_out, w_ratio_w, w_ratio_b, w_gate_w, w_gate_b,
                       probs_buf, pgen_buf, out + PTR_TOTAL);
    hipLaunchKernelGGL(k_scatter, dim3(BTq), dim3(Sq), 0, stream, story, probs_buf, pctx_buf);
    // fused GEMM + zero-fill of out slices 1..29 (ptr and gate)
    hipLaunchKernelGGL(k_logits, dim3(NCOMPUTE + NZERO + 1), dim3(256), 0, stream,
                       hT_buf, shared_emb, logits_buf, out);
    hipLaunchKernelGGL(k_stats, dim3(BTq), dim3(256), 0, stream, logits_buf, rmax_buf, rinv_buf);
    hipLaunchKernelGGL(k_combine, dim3(Vq / 256, BTq), dim3(256), 0, stream,
                       logits_buf, pctx_buf, rmax_buf, rinv_buf, pgen_buf, out);
}

// Round 10
// 766.712 us; speedup vs baseline: 2.0040x; 1.0487x over previous
//
#include <hip/hip_runtime.h>

#define Bq 16
#define Sq 512
#define Dq 400
#define Vq 32000
#define Tq 8
#define NSq 30
#define NGq 3
#define BTq (Bq*Tq)                     // 128
#define SLICE 4096000                   // Bq*Tq*Vq, one ptr slice (elems)
#define PTR_TOTAL (30ull*SLICE)         // 122,880,000
#define GATE_TOTAL (NSq*Bq*NGq)         // 1440

// k_logits fused grid: 250 compute blocks + zero-fill blocks
#define NCOMPUTE 250
#define NZERO 1813                      // 29*SLICE/4 = 29,696,000 float4; 16384/block
#define ZPER 16384                      // float4 per zero block (64 per thread)

__device__ inline float sigmoidf_(float x) { return 1.0f / (1.0f + __expf(-x)); }

__device__ inline float blockReduceSum(float v, float* red) {
    int tid = threadIdx.x;
    #pragma unroll
    for (int o = 32; o > 0; o >>= 1) v += __shfl_down(v, o, 64);
    if ((tid & 63) == 0) red[tid >> 6] = v;
    __syncthreads();
    if (tid == 0) {
        float s = red[0];
        int nw = blockDim.x >> 6;
        for (int i = 1; i < nw; i++) s += red[i];
        red[0] = s;
    }
    __syncthreads();
    float r = red[0];
    __syncthreads();
    return r;
}

__device__ inline float blockReduceMax(float v, float* red) {
    int tid = threadIdx.x;
    #pragma unroll
    for (int o = 32; o > 0; o >>= 1) v = fmaxf(v, __shfl_down(v, o, 64));
    if ((tid & 63) == 0) red[tid >> 6] = v;
    __syncthreads();
    if (tid == 0) {
        float s = red[0];
        int nw = blockDim.x >> 6;
        for (int i = 1; i < nw; i++) s = fmaxf(s, red[i]);
        red[0] = s;
    }
    __syncthreads();
    float r = red[0];
    __syncthreads();
    return r;
}

// gi = X @ w_ih^T + b_ih (128x1200), gh = h0 @ w_hh^T + b_hh (16x1200).
// grid 64 = 16 b x 4 j-tiles(300). A rows 0..7 = x(t) (slot/emb gather), row 8 = h0.
// Weights read ~4x total (vs 128x in the old per-(b,t) kernel).
__global__ __launch_bounds__(256) void k_gates(const float* __restrict__ enc_hidden,
                                               const float* __restrict__ shared_emb,
                                               const float* __restrict__ slot_emb,
                                               const float* __restrict__ w_ih,
                                               const float* __restrict__ w_hh,
                                               const float* __restrict__ b_ih,
                                               const float* __restrict__ b_hh,
                                               const int* __restrict__ trg,
                                               float* __restrict__ gi, float* __restrict__ gh) {
    __shared__ float A[9][Dq];
    __shared__ int toks[8];
    int b = blockIdx.x >> 2, jt = blockIdx.x & 3;
    int tid = threadIdx.x;
    if (tid < 7) toks[tid + 1] = trg[b * (NSq * Tq) + tid];
    __syncthreads();
    for (int idx = tid; idx < 900; idx += 256) {      // 9 rows x 100 float4
        int r = idx / 100, q = idx - r * 100;
        const float4* src;
        if (r == 8)      src = (const float4*)(enc_hidden + b * Dq);
        else if (r == 0) src = (const float4*)slot_emb;
        else             src = (const float4*)(shared_emb + (size_t)toks[r] * Dq);
        *(float4*)&A[r][4 * q] = src[q];
    }
    __syncthreads();
    for (int o = tid; o < 2700; o += 256) {           // 9 rows x 300 j
        int r = o / 300, jj = o - r * 300;
        int j = jt * 300 + jj;
        const float* w = (r == 8) ? w_hh : w_ih;
        const float4* w4 = (const float4*)(w + (size_t)j * Dq);
        const float4* a4 = (const float4*)&A[r][0];
        float acc = (r == 8) ? b_hh[j] : b_ih[j];
        #pragma unroll 4
        for (int q = 0; q < Dq / 4; ++q) {
            float4 wv = w4[q], av = a4[q];
            acc += av.x * wv.x + av.y * wv.y + av.z * wv.z + av.w * wv.w;
        }
        if (r == 8) gh[b * 1200 + j] = acc;
        else        gi[(b * 8 + r) * 1200 + j] = acc;
    }
}

// GRU elementwise + scores + softmax + scatter(probs->pctx) + context(RAW scores)
// + p_gen + gate0 + hT write. block=512, one per (b,t).
__global__ __launch_bounds__(512) void k_attn(const float* __restrict__ gi,
                                              const float* __restrict__ gh,
                                              const float* __restrict__ enc_hidden,
                                              const float* __restrict__ shared_emb,
                                              const float* __restrict__ slot_emb,
                                              const int* __restrict__ trg,
                                              const float* __restrict__ enc_out,
                                              const int* __restrict__ story,
                                              const float* __restrict__ w_ratio_w,
                                              const float* __restrict__ w_ratio_b,
                                              const float* __restrict__ w_gate_w,
                                              const float* __restrict__ w_gate_b,
                                              float* __restrict__ pctx, float* __restrict__ pgen,
                                              float* __restrict__ hT, float* __restrict__ out_gate) {
    __shared__ float h_l[Dq], ctx_l[Dq], x_l[Dq], sc_l[Sq], red[8];
    int bt = blockIdx.x, b = bt >> 3, t = bt & 7;
    int tid = threadIdx.x;
    if (tid < Dq) {
        int d = tid;
        float x = (t == 0) ? slot_emb[d]
                           : shared_emb[(size_t)trg[b * (NSq * Tq) + (t - 1)] * Dq + d];
        float h0 = enc_hidden[b * Dq + d];
        const float* gib = gi + bt * 1200;
        const float* ghb = gh + b * 1200;
        float r_ = sigmoidf_(gib[d] + ghb[d]);
        float z  = sigmoidf_(gib[Dq + d] + ghb[Dq + d]);
        float n  = tanhf(gib[2 * Dq + d] + r_ * ghb[2 * Dq + d]);
        float h  = (1.0f - z) * n + z * h0;
        h_l[d] = h; x_l[d] = x;
        hT[d * BTq + bt] = h;
    }
    __syncthreads();
    {   // scores: one s per thread
        const float4* e4 = (const float4*)(enc_out + ((size_t)(b * Sq + tid)) * Dq);
        float acc = 0.0f;
        for (int q = 0; q < Dq / 4; ++q) {
            float4 p = e4[q];
            int k = 4 * q;
            acc += h_l[k]*p.x + h_l[k+1]*p.y + h_l[k+2]*p.z + h_l[k+3]*p.w;
        }
        sc_l[tid] = acc;
    }
    __syncthreads();
    float myv = sc_l[tid];
    float m = blockReduceMax(myv, red);
    float e = __expf(myv - m);
    float ssum = blockReduceSum(e, red);
    // scatter prob directly (pctx pre-zeroed)
    atomicAdd(&pctx[(size_t)bt * Vq + story[b * Sq + tid]], e / ssum);
    // context from RAW scores
    for (int d = tid; d < Dq; d += 512) {
        float acc = 0.0f;
        #pragma unroll 8
        for (int s = 0; s < Sq; ++s)
            acc += sc_l[s] * enc_out[((size_t)(b * Sq + s)) * Dq + d];
        ctx_l[d] = acc;
    }
    __syncthreads();
    {   // p_gen = sigmoid([h,ctx,X] . w_ratio + b)
        float part = 0.0f;
        for (int i = tid; i < 1200; i += 512) {
            float v = (i < Dq) ? h_l[i] : (i < 2 * Dq ? ctx_l[i - Dq] : x_l[i - 2 * Dq]);
            part += v * w_ratio_w[i];
        }
        float tot = blockReduceSum(part, red);
        if (tid == 0) pgen[bt] = sigmoidf_(tot + w_ratio_b[0]);
    }
    if (t == 0) {
        for (int g = 0; g < NGq; ++g) {
            float part = 0.0f;
            for (int d = tid; d < Dq; d += 512) part += ctx_l[d] * w_gate_w[g * Dq + d];
            float tot = blockReduceSum(part, red);
            if (tid == 0) out_gate[b * NGq + g] = tot + w_gate_b[g];
        }
    }
}

// Fused: [0,250) logits GEMM blocks; [250,250+1813) zero ptr slices 1..29;
// last block zeroes gate slices 1..29. Zero-write BW overlaps GEMM compute.
#define TVL 128
#define CKL 40
__global__ __launch_bounds__(256) void k_logits(const float* __restrict__ hT,
                                                const float* __restrict__ emb,
                                                float* __restrict__ logits,
                                                float* __restrict__ out) {
    __shared__ float eT[CKL][132];
    __shared__ float hL[CKL][132];
    int bid = blockIdx.x;
    int tid = threadIdx.x;
    if (bid >= NCOMPUTE) {
        int zb = bid - NCOMPUTE;
        float4 z = make_float4(0.0f, 0.0f, 0.0f, 0.0f);
        if (zb < NZERO) {
            float4* dst = (float4*)(out + (size_t)SLICE);
            const size_t total = 29ull * SLICE / 4;   // 29,696,000 float4
            size_t base = (size_t)zb * ZPER + tid;
            #pragma unroll
            for (int r = 0; r < ZPER / 256; ++r) {
                size_t idx = base + (size_t)r * 256;
                if (idx < total) dst[idx] = z;
            }
        } else {
            float4* g = (float4*)(out + PTR_TOTAL + Bq * NGq);
            for (int i = tid; i < (GATE_TOTAL - Bq * NGq) / 4; i += 256) g[i] = z;
        }
        return;
    }
    int v0 = bid * TVL;
    int tx = tid & 15, ty = tid >> 4;
    float acc[8][8];
    #pragma unroll
    for (int j = 0; j < 8; ++j)
        #pragma unroll
        for (int i = 0; i < 8; ++i) acc[j][i] = 0.0f;

    for (int c = 0; c < Dq / CKL; ++c) {
        int k0 = c * CKL;
        const float4* hg = (const float4*)(hT + (size_t)k0 * BTq);
        #pragma unroll
        for (int r = 0; r < 5; ++r) {
            int idx = tid + 256 * r;
            int k = idx >> 5, c4 = idx & 31;
            float4 vd = hg[idx];
            *(float4*)&hL[k][4 * c4] = vd;
        }
        #pragma unroll
        for (int r = 0; r < 5; ++r) {
            int idx = tid + 256 * r;
            int v = idx / 10, q = idx - 10 * v;
            float4 vd = *(const float4*)(emb + (size_t)(v0 + v) * Dq + k0 + 4 * q);
            eT[4*q+0][v] = vd.x; eT[4*q+1][v] = vd.y; eT[4*q+2][v] = vd.z; eT[4*q+3][v] = vd.w;
        }
        __syncthreads();
        #pragma unroll 4
        for (int k = 0; k < CKL; ++k) {
            float4 h0 = *(const float4*)&hL[k][8 * ty];
            float4 h1 = *(const float4*)&hL[k][8 * ty + 4];
            float4 e0 = *(const float4*)&eT[k][8 * tx];
            float4 e1 = *(const float4*)&eT[k][8 * tx + 4];
            float hv[8] = {h0.x, h0.y, h0.z, h0.w, h1.x, h1.y, h1.z, h1.w};
            float ev[8] = {e0.x, e0.y, e0.z, e0.w, e1.x, e1.y, e1.z, e1.w};
            #pragma unroll
            for (int j = 0; j < 8; ++j)
                #pragma unroll
                for (int i = 0; i < 8; ++i)
                    acc[j][i] += hv[j] * ev[i];
        }
        __syncthreads();
    }
    #pragma unroll
    for (int j = 0; j < 8; ++j) {
        int bt = 8 * ty + j;
        float* dst = logits + (size_t)bt * Vq + v0 + 8 * tx;
        *(float4*)dst       = make_float4(acc[j][0], acc[j][1], acc[j][2], acc[j][3]);
        *(float4*)(dst + 4) = make_float4(acc[j][4], acc[j][5], acc[j][6], acc[j][7]);
    }
}

// fused softmax stats + combine: one block per bt row. 3 passes over a 128 KB
// row (passes 2-3 L2-hot).
__global__ __launch_bounds__(512) void k_final(const float* __restrict__ logits,
                                               const float* __restrict__ pctx,
                                               const float* __restrict__ pgen,
                                               float* __restrict__ out) {
    __shared__ float red[8];
    int bt = blockIdx.x, tid = threadIdx.x;
    const float* lr = logits + (size_t)bt * Vq;
    float m = -1e30f;
    for (int v = tid; v < Vq; v += 512) m = fmaxf(m, lr[v]);
    m = blockReduceMax(m, red);
    float s = 0.0f;
    for (int v = tid; v < Vq; v += 512) s += __expf(lr[v] - m);
    s = blockReduceSum(s, red);
    float inv = 1.0f / s, pg = pgen[bt], cg = 1.0f - pg;
    const float4* l4 = (const float4*)lr;
    const float4* p4 = (const float4*)(pctx + (size_t)bt * Vq);
    float4* o4 = (float4*)(out + (size_t)bt * Vq);
    for (int i = tid; i < Vq / 4; i += 512) {
        float4 lv = l4[i], pv = p4[i];
        o4[i] = make_float4(pg * __expf(lv.x - m) * inv + cg * pv.x,
                            pg * __expf(lv.y - m) * inv + cg * pv.y,
                            pg * __expf(lv.z - m) * inv + cg * pv.z,
                            pg * __expf(lv.w - m) * inv + cg * pv.w);
    }
}

extern "C" void kernel_launch(void* const* d_in, const int* in_sizes, int n_in,
                              void* d_out, int out_size, void* d_ws, size_t ws_size,
                              hipStream_t stream) {
    const float* enc_hidden = (const float*)d_in[0];
    const float* enc_out    = (const float*)d_in[1];
    const int*   story      = (const int*)d_in[2];
    const int*   trg        = (const int*)d_in[3];
    const float* shared_emb = (const float*)d_in[4];
    const float* slot_emb   = (const float*)d_in[5];
    const float* w_ih       = (const float*)d_in[6];
    const float* w_hh       = (const float*)d_in[7];
    const float* b_ih       = (const float*)d_in[8];
    const float* b_hh       = (const float*)d_in[9];
    const float* w_ratio_w  = (const float*)d_in[10];
    const float* w_ratio_b  = (const float*)d_in[11];
    const float* w_gate_w   = (const float*)d_in[12];
    const float* w_gate_b   = (const float*)d_in[13];

    float* out = (float*)d_out;

    // All scratch in d_ws (~33.7 MB of the ~1.97 GB workspace).
    float* ws = (float*)d_ws;
    float* logits_buf = ws;                        // 4,096,000 f
    float* pctx_buf   = ws + (size_t)SLICE;        // 4,096,000 f
    float* gi_buf     = ws + 2 * (size_t)SLICE;    // 153,600 f
    float* gh_buf     = gi_buf + 153600;           // 19,200 f
    float* hT_buf     = gh_buf + 19200;            // 51,200 f
    float* pgen_buf   = hT_buf + 51200;            // 128 f

    // zero-init only pctx (scatter-add target)
    hipMemsetAsync(pctx_buf, 0, (size_t)SLICE * sizeof(float), stream);

    hipLaunchKernelGGL(k_gates, dim3(64), dim3(256), 0, stream,
                       enc_hidden, shared_emb, slot_emb, w_ih, w_hh, b_ih, b_hh, trg,
                       gi_buf, gh_buf);
    hipLaunchKernelGGL(k_attn, dim3(BTq), dim3(512), 0, stream,
                       gi_buf, gh_buf, enc_hidden, shared_emb, slot_emb, trg,
                       enc_out, story, w_ratio_w, w_ratio_b, w_gate_w, w_gate_b,
                       pctx_buf, pgen_buf, hT_buf, out + PTR_TOTAL);
    // fused GEMM + zero-fill of out slices 1..29 (ptr and gate)
    hipLaunchKernelGGL(k_logits, dim3(NCOMPUTE + NZERO + 1), dim3(256), 0, stream,
                       hT_buf, shared_emb, logits_buf, out);
    hipLaunchKernelGGL(k_final, dim3(BTq), dim3(512), 0, stream,
                       logits_buf, pctx_buf, pgen_buf, out);
}